// Round 10
// baseline (3506.321 us; speedup 1.0000x reference)
//
#include <hip/hip_runtime.h>
#include <hip/hip_bf16.h>

typedef __bf16 bf16;
typedef __bf16 bf16x8 __attribute__((ext_vector_type(8)));
typedef __bf16 bf16x4 __attribute__((ext_vector_type(4)));
typedef float  f32x4  __attribute__((ext_vector_type(4)));

#define AS1 __attribute__((address_space(1)))
#define AS3 __attribute__((address_space(3)))

// ---------------------------------------------------------------------------
// f32 -> bf16 convert, up to 5 tensors per launch, strided rows.
// ---------------------------------------------------------------------------
struct CvtArgs {
    const float* src[5];
    bf16* dst[5];
    int rows[5], cols[5], src_ld[5];
};

__global__ __launch_bounds__(256)
void cvt_kernel(CvtArgs a)
{
    const int t = blockIdx.y;
    const float* s = a.src[t];
    bf16* d = a.dst[t];
    const int cols = a.cols[t];
    const long total = (long)a.rows[t] * cols;
    const int ld = a.src_ld[t];
    for (long i = ((long)blockIdx.x * 256 + threadIdx.x) * 4; i < total;
         i += (long)gridDim.x * 1024) {
        long r = i / cols, c = i - r * cols;      // cols % 4 == 0: chunks don't cross rows
        float4 v = *reinterpret_cast<const float4*>(s + r * ld + c);
        bf16x4 o; o[0] = (bf16)v.x; o[1] = (bf16)v.y; o[2] = (bf16)v.z; o[3] = (bf16)v.w;
        *reinterpret_cast<bf16x4*>(d + i) = o;
    }
}

// ---------------------------------------------------------------------------
// Y -> hs16 post-pass: Yf[t*3584 + 4*d + b] = h_t[b][d] (fp32, scan sync buf)
// -> hs16[b*917504 + t*896 + d] (bf16, GEMM layout). 22 MB, ~15 us.
// ---------------------------------------------------------------------------
__global__ __launch_bounds__(256)
void y2hs_kernel(const float* __restrict__ Yf, bf16* __restrict__ hs16)
{
    int gid = blockIdx.x * 256 + threadIdx.x;   // 0 .. 229375
    int t = gid / 224;
    int d = (gid - t * 224) * 4;                // 4 dims per thread
    const f32x4* src = reinterpret_cast<const f32x4*>(Yf + (long)t * 3584 + 4 * d);
    f32x4 v0 = src[0], v1 = src[1], v2 = src[2], v3 = src[3];  // v_j = dim d+j, [b0..b3]
    #pragma unroll
    for (int b = 0; b < 4; ++b) {
        bf16x4 o; o[0] = (bf16)v0[b]; o[1] = (bf16)v1[b]; o[2] = (bf16)v2[b]; o[3] = (bf16)v3[b];
        *reinterpret_cast<bf16x4*>(hs16 + (long)b * 917504 + (long)t * 896 + d) = o;
    }
}

// ---------------------------------------------------------------------------
// GEMM (m97 structure): C[M,N] = A[M,K] * B[N,K]^T (+bias). bf16 in, fp32 acc.
// 128x128 tile, BK=64, 4 waves, global_load_lds width-16, linear LDS.
// ---------------------------------------------------------------------------
__global__ __launch_bounds__(256, 2)
void gemm_bf16_kernel(const bf16* __restrict__ A, const bf16* __restrict__ B,
                      const float* __restrict__ bias,
                      float* __restrict__ Cf, bf16* __restrict__ Cb,
                      int M, int N, int K)
{
    __shared__ bf16 As[128 * 64];
    __shared__ bf16 Bs[128 * 64];
    const int tid = threadIdx.x;
    const long bm = (long)blockIdx.y * 128;
    const long bn = (long)blockIdx.x * 128;
    const int w  = tid >> 6, l = tid & 63;
    const int wm = (w >> 1) * 64, wn = (w & 1) * 64;
    const int lr = l & 15, lk = (l >> 4) * 8;

    const int srow = tid >> 3;          // 0..31
    const int scol = (tid & 7) * 8;     // 0,8,..,56
    const bf16* Ag = A + (bm + srow) * (long)K + scol;
    const bf16* Bg = B + (bn + srow) * (long)K + scol;
    bf16* AsW = As + srow * 64 + scol;
    bf16* BsW = Bs + srow * 64 + scol;

    f32x4 acc[4][4];
    #pragma unroll
    for (int i = 0; i < 4; ++i)
        #pragma unroll
        for (int j = 0; j < 4; ++j)
            acc[i][j] = f32x4{0.f, 0.f, 0.f, 0.f};

    for (int kt = 0; kt < K; kt += 64) {
        #pragma unroll
        for (int i = 0; i < 4; ++i) {
            __builtin_amdgcn_global_load_lds(
                (const AS1 void*)(Ag + (long)i * 32 * K + kt),
                (AS3 void*)(AsW + i * 2048), 16, 0, 0);
            __builtin_amdgcn_global_load_lds(
                (const AS1 void*)(Bg + (long)i * 32 * K + kt),
                (AS3 void*)(BsW + i * 2048), 16, 0, 0);
        }
        __syncthreads();
        #pragma unroll
        for (int kk = 0; kk < 64; kk += 32) {
            bf16x8 a[4], b[4];
            #pragma unroll
            for (int i = 0; i < 4; ++i) {
                a[i] = *reinterpret_cast<const bf16x8*>(&As[(wm + i * 16 + lr) * 64 + kk + lk]);
                b[i] = *reinterpret_cast<const bf16x8*>(&Bs[(wn + i * 16 + lr) * 64 + kk + lk]);
            }
            #pragma unroll
            for (int i = 0; i < 4; ++i)
                #pragma unroll
                for (int j = 0; j < 4; ++j)
                    acc[i][j] = __builtin_amdgcn_mfma_f32_16x16x32_bf16(a[i], b[j], acc[i][j], 0, 0, 0);
        }
        __syncthreads();
    }
    const int crow = wm + (l >> 4) * 4;
    const int ccol = wn + (l & 15);
    #pragma unroll
    for (int i = 0; i < 4; ++i)
        #pragma unroll
        for (int j = 0; j < 4; ++j) {
            long col = bn + ccol + j * 16;
            float bv = bias ? bias[col] : 0.0f;
            #pragma unroll
            for (int r = 0; r < 4; ++r) {
                long row = bm + crow + i * 16 + r;
                float v = acc[i][j][r] + bv;
                if (Cf) Cf[row * (long)N + col] = v;
                if (Cb) Cb[row * (long)N + col] = (bf16)v;
            }
        }
}

// ---------------------------------------------------------------------------
// Scan sync (PROVEN r5/r6): data-is-the-flag on Y (u64 pairs), relaxed
// agent-scope atomics, parallel poll + s_sleep backoff, full __syncthreads.
// r10 change: NO hs16 stores in the loop (post-pass y2hs does the layout
// conversion) -- the end-of-step vmcnt drain now covers only 2 u64 stores.
// ---------------------------------------------------------------------------
#define SENT64 0xFFFFFFFFFFFFFFFFull
#define NBLK_SCAN 56

__device__ __forceinline__ float lo32f(unsigned long long v) {
    return __builtin_bit_cast(float, (unsigned int)v);
}
__device__ __forceinline__ float hi32f(unsigned long long v) {
    return __builtin_bit_cast(float, (unsigned int)(v >> 32));
}

__device__ __forceinline__ void scan_body(const float* __restrict__ Amat,
                                          const float* __restrict__ xB,
                                          unsigned long long* __restrict__ Y,
                                          float* hS)
{
    __builtin_amdgcn_s_setprio(3);
    const int tid = threadIdx.x;
    const int bi  = blockIdx.x;
    const int kq  = tid & 31;      // 32 k-slices of 28
    const int rg  = tid >> 5;      // 16 rows per block
    const int row = bi * 16 + rg;

    float4 areg[7];
    {
        const float4* Ap = reinterpret_cast<const float4*>(Amat + (long)row * 896 + kq * 28);
        #pragma unroll
        for (int j = 0; j < 7; ++j) areg[j] = Ap[j];
    }

    const int d0 = tid;
    const int d1 = tid + 512;
    const bool two = (tid < 384);  // wave-uniform

    for (int t = 1; t <= 1024; ++t) {
        const long so = (long)(t - 1) * 896 + row;
        float xb0 = 0, xb1 = 0, xb2 = 0, xb3 = 0;
        if (kq == 0) {
            xb0 = xB[so];
            xb1 = xB[so +  917504];
            xb2 = xB[so + 1835008];
            xb3 = xB[so + 2752512];
        }

        if (t == 1) {
            #pragma unroll
            for (int j = 0; j < 7; ++j) hS[tid + j * 512] = 0.0f;
        } else {
            const unsigned long long* Yp = Y + (long)(t - 2) * 1792;
            unsigned long long va, vb, vc = 0, vd = 0;
            for (;;) {
                va = __hip_atomic_load(&Yp[2 * d0],     __ATOMIC_RELAXED, __HIP_MEMORY_SCOPE_AGENT);
                vb = __hip_atomic_load(&Yp[2 * d0 + 1], __ATOMIC_RELAXED, __HIP_MEMORY_SCOPE_AGENT);
                bool ok = (va != SENT64) & (vb != SENT64);
                if (two) {
                    vc = __hip_atomic_load(&Yp[2 * d1],     __ATOMIC_RELAXED, __HIP_MEMORY_SCOPE_AGENT);
                    vd = __hip_atomic_load(&Yp[2 * d1 + 1], __ATOMIC_RELAXED, __HIP_MEMORY_SCOPE_AGENT);
                    ok &= (vc != SENT64) & (vd != SENT64);
                }
                if (ok) break;
                __builtin_amdgcn_s_sleep(1);
            }
            hS[       d0] = lo32f(va);
            hS[ 896 + d0] = hi32f(va);
            hS[1792 + d0] = lo32f(vb);
            hS[2688 + d0] = hi32f(vb);
            if (two) {
                hS[       d1] = lo32f(vc);
                hS[ 896 + d1] = hi32f(vc);
                hS[1792 + d1] = lo32f(vd);
                hS[2688 + d1] = hi32f(vd);
            }
        }
        __syncthreads();

        const float4* h0p = reinterpret_cast<const float4*>(hS +    0 + kq * 28);
        const float4* h1p = reinterpret_cast<const float4*>(hS +  896 + kq * 28);
        const float4* h2p = reinterpret_cast<const float4*>(hS + 1792 + kq * 28);
        const float4* h3p = reinterpret_cast<const float4*>(hS + 2688 + kq * 28);
        float a0 = 0, a1 = 0, a2 = 0, a3 = 0;
        #pragma unroll
        for (int j = 0; j < 7; ++j) {
            float4 a = areg[j];
            float4 v0 = h0p[j]; a0 += a.x*v0.x + a.y*v0.y + a.z*v0.z + a.w*v0.w;
            float4 v1 = h1p[j]; a1 += a.x*v1.x + a.y*v1.y + a.z*v1.z + a.w*v1.w;
            float4 v2 = h2p[j]; a2 += a.x*v2.x + a.y*v2.y + a.z*v2.z + a.w*v2.w;
            float4 v3 = h3p[j]; a3 += a.x*v3.x + a.y*v3.y + a.z*v3.z + a.w*v3.w;
        }
        a0 += __shfl_xor(a0, 16); a1 += __shfl_xor(a1, 16); a2 += __shfl_xor(a2, 16); a3 += __shfl_xor(a3, 16);
        a0 += __shfl_xor(a0,  8); a1 += __shfl_xor(a1,  8); a2 += __shfl_xor(a2,  8); a3 += __shfl_xor(a3,  8);
        a0 += __shfl_xor(a0,  4); a1 += __shfl_xor(a1,  4); a2 += __shfl_xor(a2,  4); a3 += __shfl_xor(a3,  4);
        a0 += __shfl_xor(a0,  2); a1 += __shfl_xor(a1,  2); a2 += __shfl_xor(a2,  2); a3 += __shfl_xor(a3,  2);
        a0 += __shfl_xor(a0,  1); a1 += __shfl_xor(a1,  1); a2 += __shfl_xor(a2,  1); a3 += __shfl_xor(a3,  1);

        if (kq == 0) {
            float z[4] = { a0 + xb0, a1 + xb1, a2 + xb2, a3 + xb3 };
            float hv[4];
            #pragma unroll
            for (int b = 0; b < 4; ++b) {
                float zz = fminf(fmaxf(z[b], -15.f), 15.f);
                float e  = __expf(2.f * zz);
                hv[b] = (e - 1.f) / (e + 1.f);
            }
            unsigned long long lo =
                (unsigned long long)__builtin_bit_cast(unsigned int, hv[0]) |
                ((unsigned long long)__builtin_bit_cast(unsigned int, hv[1]) << 32);
            unsigned long long hi =
                (unsigned long long)__builtin_bit_cast(unsigned int, hv[2]) |
                ((unsigned long long)__builtin_bit_cast(unsigned int, hv[3]) << 32);
            unsigned long long* yp = Y + (long)(t - 1) * 1792 + 2 * row;
            __hip_atomic_store(&yp[0], lo, __ATOMIC_RELAXED, __HIP_MEMORY_SCOPE_AGENT);
            __hip_atomic_store(&yp[1], hi, __ATOMIC_RELAXED, __HIP_MEMORY_SCOPE_AGENT);
        }
        __syncthreads();
    }
}

// ---------------------------------------------------------------------------
// Flash attention body (r9-proven): vectorized staging + vectorized QK inner.
// ---------------------------------------------------------------------------
__device__ __forceinline__ void attn_body(const float* __restrict__ qkv,
                                          bf16* __restrict__ ctx16,
                                          float* ldsf, int bid2)
{
    float* qS = ldsf;
    float* pS = qS + 1792;
    float* rS = pS + 2112;
    float* lS = rS + 32;
    bf16*  kS = (bf16*)(lS + 32);
    bf16*  vS = kS + 3840;

    const int tid = threadIdx.x;
    const int qc = bid2 & 31;
    const int h  = (bid2 >> 5) & 15;
    const int b  = bid2 >> 9;
    const long base = (long)b * 1024 * 2688;
    const int q0 = qc * 32;
    const int hoff = h * 56;

    if (tid < 448) {   // 32 rows x 14 float4-chunks
        int r = tid / 14, c = (tid - r * 14) * 4;
        float4 v = *reinterpret_cast<const float4*>(
            &qkv[base + (long)(q0 + r) * 2688 + hoff + c]);
        const float SC = 0.13363062095621f;
        *reinterpret_cast<float4*>(qS + r * 56 + c) =
            float4{v.x * SC, v.y * SC, v.z * SC, v.w * SC};
    }

    const int w = tid >> 6, l = tid & 63;
    const int qrow = 4 * w;
    const int oq = tid >> 4, ods = tid & 15;
    float m0 = -3e38f, m1 = -3e38f, m2 = -3e38f, m3 = -3e38f;
    float s_l0 = 0, s_l1 = 0, s_l2 = 0, s_l3 = 0;
    float o0 = 0, o1 = 0, o2 = 0, o3 = 0;

    for (int kt = 0; kt < 16; ++kt) {
        __syncthreads();
        for (int idx = tid; idx < 1792; idx += 512) {
            int isv = idx >= 896;
            int e = isv ? idx - 896 : idx;
            int r = e / 14, c = (e - r * 14) * 4;
            float4 v = *reinterpret_cast<const float4*>(
                &qkv[base + (long)(kt * 64 + r) * 2688 + (isv ? 1792 : 896) + hoff + c]);
            bf16x4 o; o[0] = (bf16)v.x; o[1] = (bf16)v.y; o[2] = (bf16)v.z; o[3] = (bf16)v.w;
            *reinterpret_cast<bf16x4*>((isv ? vS : kS) + r * 60 + c) = o;
        }
        __syncthreads();

        float s0 = 0, s1 = 0, s2 = 0, s3 = 0;
        const float* qp = qS + qrow * 56;
        const bf16* kp = kS + l * 60;
        #pragma unroll
        for (int d = 0; d < 56; d += 4) {
            bf16x4 k4 = *reinterpret_cast<const bf16x4*>(kp + d);
            float k0 = (float)k4[0], k1 = (float)k4[1], k2 = (float)k4[2], k3 = (float)k4[3];
            float4 q0v = *reinterpret_cast<const float4*>(qp + d);
            float4 q1v = *reinterpret_cast<const float4*>(qp + 56 + d);
            float4 q2v = *reinterpret_cast<const float4*>(qp + 112 + d);
            float4 q3v = *reinterpret_cast<const float4*>(qp + 168 + d);
            s0 += q0v.x * k0 + q0v.y * k1 + q0v.z * k2 + q0v.w * k3;
            s1 += q1v.x * k0 + q1v.y * k1 + q1v.z * k2 + q1v.w * k3;
            s2 += q2v.x * k0 + q2v.y * k1 + q2v.z * k2 + q2v.w * k3;
            s3 += q3v.x * k0 + q3v.y * k1 + q3v.z * k2 + q3v.w * k3;
        }
        float x0 = s0, x1 = s1, x2 = s2, x3 = s3;
        #pragma unroll
        for (int off = 32; off >= 1; off >>= 1) {
            x0 = fmaxf(x0, __shfl_xor(x0, off));
            x1 = fmaxf(x1, __shfl_xor(x1, off));
            x2 = fmaxf(x2, __shfl_xor(x2, off));
            x3 = fmaxf(x3, __shfl_xor(x3, off));
        }
        float nm0 = fmaxf(m0, x0), nm1 = fmaxf(m1, x1);
        float nm2 = fmaxf(m2, x2), nm3 = fmaxf(m3, x3);
        float p0 = __expf(s0 - nm0), p1 = __expf(s1 - nm1);
        float p2 = __expf(s2 - nm2), p3 = __expf(s3 - nm3);
        float sc0 = __expf(m0 - nm0), sc1 = __expf(m1 - nm1);
        float sc2 = __expf(m2 - nm2), sc3 = __expf(m3 - nm3);
        float t0 = p0, t1 = p1, t2 = p2, t3 = p3;
        #pragma unroll
        for (int off = 32; off >= 1; off >>= 1) {
            t0 += __shfl_xor(t0, off); t1 += __shfl_xor(t1, off);
            t2 += __shfl_xor(t2, off); t3 += __shfl_xor(t3, off);
        }
        s_l0 = s_l0 * sc0 + t0; s_l1 = s_l1 * sc1 + t1;
        s_l2 = s_l2 * sc2 + t2; s_l3 = s_l3 * sc3 + t3;
        m0 = nm0; m1 = nm1; m2 = nm2; m3 = nm3;
        pS[(qrow + 0) * 66 + l] = p0; pS[(qrow + 1) * 66 + l] = p1;
        pS[(qrow + 2) * 66 + l] = p2; pS[(qrow + 3) * 66 + l] = p3;
        if (l == 0) { rS[qrow] = sc0; rS[qrow+1] = sc1; rS[qrow+2] = sc2; rS[qrow+3] = sc3; }
        __syncthreads();

        float rf = rS[oq];
        o0 *= rf; o1 *= rf; o2 *= rf; o3 *= rf;
        const float* pp = pS + oq * 66;
        #pragma unroll 4
        for (int kk = 0; kk < 64; ++kk) {
            float p = pp[kk];
            const bf16* vp = vS + kk * 60 + ods;
            o0 += p * (float)vp[0];
            o1 += p * (float)vp[16];
            o2 += p * (float)vp[32];
            if (ods < 8) o3 += p * (float)vp[48];
        }
    }
    __syncthreads();
    if (l == 0) {
        lS[qrow]     = 1.f / s_l0; lS[qrow + 1] = 1.f / s_l1;
        lS[qrow + 2] = 1.f / s_l2; lS[qrow + 3] = 1.f / s_l3;
    }
    __syncthreads();
    float inv = lS[oq];
    bf16* cp = ctx16 + ((long)b * 1024 + q0 + oq) * 896 + hoff + ods;
    cp[0]  = (bf16)(o0 * inv);
    cp[16] = (bf16)(o1 * inv);
    cp[32] = (bf16)(o2 * inv);
    if (ods < 8) cp[48] = (bf16)(o3 * inv);
}

__global__ __launch_bounds__(512)
void scan_attn_kernel(const float* __restrict__ Amat, const float* __restrict__ xB,
                      unsigned long long* __restrict__ Y,
                      const float* __restrict__ qkv, bf16* __restrict__ ctx16)
{
    __shared__ float ldsf[7872];
    if (blockIdx.x < NBLK_SCAN)
        scan_body(Amat, xB, Y, ldsf);
    else
        attn_body(qkv, ctx16, ldsf, blockIdx.x - NBLK_SCAN);
}

// ---------------------------------------------------------------------------
// Two LayerNorms -> combined fp32 (gate_mix) + combined bf16 (fuse GEMM)
// ---------------------------------------------------------------------------
__global__ __launch_bounds__(256)
void ln2_kernel(const float* __restrict__ s_in, const float* __restrict__ a_in,
                const float* __restrict__ gs, const float* __restrict__ bs,
                const float* __restrict__ ga, const float* __restrict__ ba,
                float* __restrict__ comb, bf16* __restrict__ comb16)
{
    const int wv = threadIdx.x >> 6, ln = threadIdx.x & 63;
    const long row = (long)blockIdx.x * 4 + wv;
    const bool is_a = (blockIdx.y != 0);
    const float* src = (is_a ? a_in : s_in) + row * 896;
    float v[14]; float sum = 0, sq = 0;
    #pragma unroll
    for (int j = 0; j < 14; ++j) { v[j] = src[ln + j * 64]; sum += v[j]; sq += v[j] * v[j]; }
    #pragma unroll
    for (int off = 32; off >= 1; off >>= 1) { sum += __shfl_xor(sum, off); sq += __shfl_xor(sq, off); }
    const float mean = sum * (1.0f / 896.0f);
    const float var  = sq * (1.0f / 896.0f) - mean * mean;
    const float inv  = rsqrtf(var + 1e-5f);
    const float* g  = is_a ? ga : gs;
    const float* bb = is_a ? ba : bs;
    float* dst   = comb   + row * 1792 + (is_a ? 896 : 0);
    bf16*  dst16 = comb16 + row * 1792 + (is_a ? 896 : 0);
    #pragma unroll
    for (int j = 0; j < 14; ++j) {
        int i = ln + j * 64;
        float o = (v[j] - mean) * inv * g[i] + bb[i];
        dst[i] = o;
        dst16[i] = (bf16)o;
    }
}

// ---------------------------------------------------------------------------
// Gates + final mix -> d_out
// ---------------------------------------------------------------------------
__global__ __launch_bounds__(256)
void gate_mix_kernel(const float* __restrict__ fused, const float* __restrict__ gw,
                     const float* __restrict__ gb, const float* __restrict__ comb,
                     float* __restrict__ out)
{
    const int tid = threadIdx.x;
    const int seg = tid & 15;
    const long row = (long)blockIdx.x * 16 + (tid >> 4);
    const float* fr = fused + row * 896;
    float d0 = 0, d1 = 0;
    for (int i = seg; i < 896; i += 16) {
        float f = fr[i];
        d0 += f * gw[i];
        d1 += f * gw[896 + i];
    }
    #pragma unroll
    for (int off = 8; off >= 1; off >>= 1) { d0 += __shfl_xor(d0, off); d1 += __shfl_xor(d1, off); }
    float l0 = d0 + gb[0], l1 = d1 + gb[1];
    float m = fmaxf(l0, l1);
    float e0 = __expf(l0 - m), e1 = __expf(l1 - m);
    float inv = 1.0f / (e0 + e1);
    float g0 = e0 * inv, g1 = e1 * inv;
    const float* cr = comb + row * 1792;
    float* orow = out + row * 896;
    for (int i = seg; i < 896; i += 16)
        orow[i] = g0 * cr[i] + g1 * cr[896 + i];
}

// ---------------------------------------------------------------------------
extern "C" void kernel_launch(void* const* d_in, const int* in_sizes, int n_in,
                              void* d_out, int out_size, void* d_ws, size_t ws_size,
                              hipStream_t stream)
{
    (void)in_sizes; (void)n_in; (void)out_size; (void)ws_size;
    const float* x         = (const float*)d_in[0];
    const float* Amat      = (const float*)d_in[1];
    const float* Bm        = (const float*)d_in[2];
    const float* Cm        = (const float*)d_in[3];
    const float* ssm_in_w  = (const float*)d_in[4];
    const float* ssm_in_b  = (const float*)d_in[5];
    const float* ssm_out_w = (const float*)d_in[6];
    const float* ssm_out_b = (const float*)d_in[7];
    const float* qkv_w     = (const float*)d_in[8];
    const float* qkv_b     = (const float*)d_in[9];
    const float* attn_w    = (const float*)d_in[10];
    const float* attn_b    = (const float*)d_in[11];
    const float* proj_w    = (const float*)d_in[12];
    const float* proj_b    = (const float*)d_in[13];
    const float* ln_sg     = (const float*)d_in[14];
    const float* ln_sb     = (const float*)d_in[15];
    const float* ln_ag     = (const float*)d_in[16];
    const float* ln_ab     = (const float*)d_in[17];
    const float* fuse_w    = (const float*)d_in[18];
    const float* fuse_b    = (const float*)d_in[19];
    const float* gate_w    = (const float*)d_in[20];
    const float* gate_b    = (const float*)d_in[21];

    float* wsf = (float*)d_ws;
    char*  wsb = (char*)d_ws;

    // ------ workspace layout: max 146.8 MB (envelope proven r1-r9) ------
    unsigned long long* Y = (unsigned long long*)wsb;
    float* Yf       = wsf;               // Y viewed as fp32 for y2hs
    float* xB       = wsf + 3670016;
    float* qkv      = wsf + 7340032;
    float* attn_out = wsf + 18350080;
    float* ssm_out  = wsf + 22020096;
    float* combf    = wsf + 25690112;
    bf16* comb16 = (bf16*)wsb;
    bf16* ssm_in_w16 = (bf16*)(wsb + 73400320);
    bf16* Bm16       = (bf16*)(wsb + 75005952);
    bf16* qkv_w16    = (bf16*)(wsb + 76611584);
    bf16* hs16   = (bf16*)(wsb + 73400320);
    bf16* ys16   = (bf16*)(wsb + 80740352);
    bf16* Cm16        = (bf16*)(wsb + 14680064);
    bf16* ssm_out_w16 = (bf16*)(wsb + 16285696);
    bf16* attn_w16    = (bf16*)(wsb + 17891328);
    bf16* proj_w16    = (bf16*)(wsb + 19496960);
    bf16* fuse_w16    = (bf16*)(wsb + 21102592);
    bf16* ctx16  = (bf16*)(wsb + 102760448);
    bf16* t116   = (bf16*)(wsb + 110100480);
    bf16* x16    = (bf16*)(wsb + 132120576);
    bf16* xp16   = (bf16*)(wsb + 139460608);

    hipMemsetAsync(Y, 0xFF, 14680064, stream);

    // cvt#1: x + early weights
    CvtArgs c1{};
    c1.src[0] = x;        c1.dst[0] = x16;        c1.rows[0] = 1; c1.cols[0] = 3670016; c1.src_ld[0] = 3670016;
    c1.src[1] = ssm_in_w; c1.dst[1] = ssm_in_w16; c1.rows[1] = 1; c1.cols[1] = 802816;  c1.src_ld[1] = 802816;
    c1.src[2] = Bm;       c1.dst[2] = Bm16;       c1.rows[2] = 1; c1.cols[2] = 802816;  c1.src_ld[2] = 802816;
    c1.src[3] = qkv_w;    c1.dst[3] = qkv_w16;    c1.rows[3] = 1; c1.cols[3] = 2408448; c1.src_ld[3] = 2408448;
    c1.src[4] = x;        c1.dst[4] = x16;        c1.rows[4] = 1; c1.cols[4] = 0;       c1.src_ld[4] = 4;
    cvt_kernel<<<dim3(64, 4), 256, 0, stream>>>(c1);

    // front GEMMs
    gemm_bf16_kernel<<<dim3(7, 32),  256, 0, stream>>>(x16,  ssm_in_w16, ssm_in_b, nullptr, xp16, 4096, 896, 896);
    gemm_bf16_kernel<<<dim3(7, 32),  256, 0, stream>>>(xp16, Bm16,       nullptr,  xB, nullptr,  4096, 896, 896);
    gemm_bf16_kernel<<<dim3(21, 32), 256, 0, stream>>>(x16,  qkv_w16,    qkv_b,    qkv, nullptr, 4096, 2688, 896);
    // fused: scan (blocks 0..55, prio 3) + flash attention (blocks 56..2103)
    scan_attn_kernel<<<NBLK_SCAN + 2048, 512, 0, stream>>>(Amat, xB, Y, qkv, ctx16);

    // Y -> hs16 layout conversion (bit-identical to the old in-scan stores)
    y2hs_kernel<<<896, 256, 0, stream>>>(Yf, hs16);

    // cvt#2: late weights into dead xB region
    CvtArgs c2{};
    c2.src[0] = Cm;        c2.dst[0] = Cm16;        c2.rows[0] = 1;   c2.cols[0] = 802816; c2.src_ld[0] = 802816;
    c2.src[1] = ssm_out_w; c2.dst[1] = ssm_out_w16; c2.rows[1] = 1;   c2.cols[1] = 802816; c2.src_ld[1] = 802816;
    c2.src[2] = attn_w;    c2.dst[2] = attn_w16;    c2.rows[2] = 1;   c2.cols[2] = 802816; c2.src_ld[2] = 802816;
    c2.src[3] = proj_w;    c2.dst[3] = proj_w16;    c2.rows[3] = 1;   c2.cols[3] = 802816; c2.src_ld[3] = 802816;
    c2.src[4] = fuse_w;    c2.dst[4] = fuse_w16;    c2.rows[4] = 896; c2.cols[4] = 1792;   c2.src_ld[4] = 2688;
    cvt_kernel<<<dim3(64, 5), 256, 0, stream>>>(c2);

    // SSM tail
    gemm_bf16_kernel<<<dim3(7, 32), 256, 0, stream>>>(hs16, Cm16,        nullptr,   nullptr, ys16, 4096, 896, 896);
    gemm_bf16_kernel<<<dim3(7, 32), 256, 0, stream>>>(ys16, ssm_out_w16, ssm_out_b, ssm_out, nullptr, 4096, 896, 896);
    // attention tail
    gemm_bf16_kernel<<<dim3(7, 32), 256, 0, stream>>>(ctx16, attn_w16, attn_b, nullptr, t116, 4096, 896, 896);
    gemm_bf16_kernel<<<dim3(7, 32), 256, 0, stream>>>(t116,  proj_w16, proj_b, attn_out, nullptr, 4096, 896, 896);
    // norms -> combined (fp32 + bf16)
    ln2_kernel<<<dim3(1024, 2), 256, 0, stream>>>(ssm_out, attn_out, ln_sg, ln_sb, ln_ag, ln_ab, combf, comb16);
    // fused = comb16 @ fuse_w16^T + b
    gemm_bf16_kernel<<<dim3(7, 32), 256, 0, stream>>>(comb16, fuse_w16, fuse_b, ssm_out, nullptr, 4096, 896, 1792);
    // gates + mix -> out
    gate_mix_kernel<<<256, 256, 0, stream>>>(ssm_out, gate_w, gate_b, combf, (float*)d_out);
}

// Round 12
// 2938.581 us; speedup vs baseline: 1.1932x; 1.1932x over previous
//
#include <hip/hip_runtime.h>
#include <hip/hip_bf16.h>

typedef __bf16 bf16;
typedef __bf16 bf16x8 __attribute__((ext_vector_type(8)));
typedef __bf16 bf16x4 __attribute__((ext_vector_type(4)));
typedef float  f32x4  __attribute__((ext_vector_type(4)));

#define AS1 __attribute__((address_space(1)))
#define AS3 __attribute__((address_space(3)))

// ---------------------------------------------------------------------------
// f32 -> bf16 convert, up to 5 tensors per launch, strided rows.
// ---------------------------------------------------------------------------
struct CvtArgs {
    const float* src[5];
    bf16* dst[5];
    int rows[5], cols[5], src_ld[5];
};

__global__ __launch_bounds__(256)
void cvt_kernel(CvtArgs a)
{
    const int t = blockIdx.y;
    const float* s = a.src[t];
    bf16* d = a.dst[t];
    const int cols = a.cols[t];
    const long total = (long)a.rows[t] * cols;
    const int ld = a.src_ld[t];
    for (long i = ((long)blockIdx.x * 256 + threadIdx.x) * 4; i < total;
         i += (long)gridDim.x * 1024) {
        long r = i / cols, c = i - r * cols;      // cols % 4 == 0: chunks don't cross rows
        float4 v = *reinterpret_cast<const float4*>(s + r * ld + c);
        bf16x4 o; o[0] = (bf16)v.x; o[1] = (bf16)v.y; o[2] = (bf16)v.z; o[3] = (bf16)v.w;
        *reinterpret_cast<bf16x4*>(d + i) = o;
    }
}

// ---------------------------------------------------------------------------
// GEMM (m97 structure): C[M,N] = A[M,K] * B[N,K]^T (+bias). bf16 in, fp32 acc.
// 128x128 tile, BK=64, 4 waves, global_load_lds width-16, linear LDS. M=4096.
// gemm2_kernel: TWO independent problems batched on blockIdx.z.
// RACE RULE (r11 lesson): problems batched in one launch must have fully
// disjoint {read set} x {write set} -- dead-region reuse is only legal
// across launch boundaries.
// ---------------------------------------------------------------------------
struct GemmProb {
    const bf16* A;
    const bf16* B;
    const float* bias;
    float* Cf;
    bf16* Cb;
    int N, K, gx;
};

__device__ __forceinline__ void gemm_body(const GemmProb& p,
                                          bf16* As, bf16* Bs)
{
    const int N = p.N, K = p.K;
    const int tid = threadIdx.x;
    const long bm = (long)blockIdx.y * 128;
    const long bn = (long)blockIdx.x * 128;
    const int w  = tid >> 6, l = tid & 63;
    const int wm = (w >> 1) * 64, wn = (w & 1) * 64;
    const int lr = l & 15, lk = (l >> 4) * 8;

    const int srow = tid >> 3;          // 0..31
    const int scol = (tid & 7) * 8;     // 0,8,..,56
    const bf16* Ag = p.A + (bm + srow) * (long)K + scol;
    const bf16* Bg = p.B + (bn + srow) * (long)K + scol;
    bf16* AsW = As + srow * 64 + scol;
    bf16* BsW = Bs + srow * 64 + scol;

    f32x4 acc[4][4];
    #pragma unroll
    for (int i = 0; i < 4; ++i)
        #pragma unroll
        for (int j = 0; j < 4; ++j)
            acc[i][j] = f32x4{0.f, 0.f, 0.f, 0.f};

    for (int kt = 0; kt < K; kt += 64) {
        #pragma unroll
        for (int i = 0; i < 4; ++i) {
            __builtin_amdgcn_global_load_lds(
                (const AS1 void*)(Ag + (long)i * 32 * K + kt),
                (AS3 void*)(AsW + i * 2048), 16, 0, 0);
            __builtin_amdgcn_global_load_lds(
                (const AS1 void*)(Bg + (long)i * 32 * K + kt),
                (AS3 void*)(BsW + i * 2048), 16, 0, 0);
        }
        __syncthreads();
        #pragma unroll
        for (int kk = 0; kk < 64; kk += 32) {
            bf16x8 a[4], b[4];
            #pragma unroll
            for (int i = 0; i < 4; ++i) {
                a[i] = *reinterpret_cast<const bf16x8*>(&As[(wm + i * 16 + lr) * 64 + kk + lk]);
                b[i] = *reinterpret_cast<const bf16x8*>(&Bs[(wn + i * 16 + lr) * 64 + kk + lk]);
            }
            #pragma unroll
            for (int i = 0; i < 4; ++i)
                #pragma unroll
                for (int j = 0; j < 4; ++j)
                    acc[i][j] = __builtin_amdgcn_mfma_f32_16x16x32_bf16(a[i], b[j], acc[i][j], 0, 0, 0);
        }
        __syncthreads();
    }
    const int crow = wm + (l >> 4) * 4;
    const int ccol = wn + (l & 15);
    #pragma unroll
    for (int i = 0; i < 4; ++i)
        #pragma unroll
        for (int j = 0; j < 4; ++j) {
            long col = bn + ccol + j * 16;
            float bv = p.bias ? p.bias[col] : 0.0f;
            #pragma unroll
            for (int r = 0; r < 4; ++r) {
                long row = bm + crow + i * 16 + r;
                float v = acc[i][j][r] + bv;
                if (p.Cf) p.Cf[row * (long)N + col] = v;
                if (p.Cb) p.Cb[row * (long)N + col] = (bf16)v;
            }
        }
}

__global__ __launch_bounds__(256, 2)
void gemm_bf16_kernel(GemmProb p)
{
    __shared__ bf16 As[128 * 64];
    __shared__ bf16 Bs[128 * 64];
    gemm_body(p, As, Bs);
}

__global__ __launch_bounds__(256, 2)
void gemm2_kernel(GemmProb p0, GemmProb p1)
{
    __shared__ bf16 As[128 * 64];
    __shared__ bf16 Bs[128 * 64];
    const GemmProb& p = blockIdx.z ? p1 : p0;
    if ((int)blockIdx.x >= p.gx) return;
    gemm_body(p, As, Bs);
}

// ---------------------------------------------------------------------------
// Scan sync (r9-proven config, byte-identical logic): data-is-the-flag on Y
// (u64 pairs), relaxed agent-scope atomics, parallel poll + s_sleep backoff,
// full __syncthreads barriers, in-loop bf16 hs16 stores. Scan loop timing is
// at an empirical floor (r5/r8/r10 all failed to beat it) -- do not touch.
// ---------------------------------------------------------------------------
#define SENT64 0xFFFFFFFFFFFFFFFFull
#define NBLK_SCAN 56

__device__ __forceinline__ float lo32f(unsigned long long v) {
    return __builtin_bit_cast(float, (unsigned int)v);
}
__device__ __forceinline__ float hi32f(unsigned long long v) {
    return __builtin_bit_cast(float, (unsigned int)(v >> 32));
}

__device__ __forceinline__ void scan_body(const float* __restrict__ Amat,
                                          const float* __restrict__ xB,
                                          bf16* __restrict__ hs16,
                                          unsigned long long* __restrict__ Y,
                                          float* hS)
{
    __builtin_amdgcn_s_setprio(3);
    const int tid = threadIdx.x;
    const int bi  = blockIdx.x;
    const int kq  = tid & 31;      // 32 k-slices of 28
    const int rg  = tid >> 5;      // 16 rows per block
    const int row = bi * 16 + rg;

    float4 areg[7];
    {
        const float4* Ap = reinterpret_cast<const float4*>(Amat + (long)row * 896 + kq * 28);
        #pragma unroll
        for (int j = 0; j < 7; ++j) areg[j] = Ap[j];
    }

    const int d0 = tid;
    const int d1 = tid + 512;
    const bool two = (tid < 384);  // wave-uniform

    for (int t = 1; t <= 1024; ++t) {
        const long so = (long)(t - 1) * 896 + row;
        float xb0 = 0, xb1 = 0, xb2 = 0, xb3 = 0;
        if (kq == 0) {
            xb0 = xB[so];
            xb1 = xB[so +  917504];
            xb2 = xB[so + 1835008];
            xb3 = xB[so + 2752512];
        }

        if (t == 1) {
            #pragma unroll
            for (int j = 0; j < 7; ++j) hS[tid + j * 512] = 0.0f;
        } else {
            const unsigned long long* Yp = Y + (long)(t - 2) * 1792;
            unsigned long long va, vb, vc = 0, vd = 0;
            for (;;) {
                va = __hip_atomic_load(&Yp[2 * d0],     __ATOMIC_RELAXED, __HIP_MEMORY_SCOPE_AGENT);
                vb = __hip_atomic_load(&Yp[2 * d0 + 1], __ATOMIC_RELAXED, __HIP_MEMORY_SCOPE_AGENT);
                bool ok = (va != SENT64) & (vb != SENT64);
                if (two) {
                    vc = __hip_atomic_load(&Yp[2 * d1],     __ATOMIC_RELAXED, __HIP_MEMORY_SCOPE_AGENT);
                    vd = __hip_atomic_load(&Yp[2 * d1 + 1], __ATOMIC_RELAXED, __HIP_MEMORY_SCOPE_AGENT);
                    ok &= (vc != SENT64) & (vd != SENT64);
                }
                if (ok) break;
                __builtin_amdgcn_s_sleep(1);
            }
            hS[       d0] = lo32f(va);
            hS[ 896 + d0] = hi32f(va);
            hS[1792 + d0] = lo32f(vb);
            hS[2688 + d0] = hi32f(vb);
            if (two) {
                hS[       d1] = lo32f(vc);
                hS[ 896 + d1] = hi32f(vc);
                hS[1792 + d1] = lo32f(vd);
                hS[2688 + d1] = hi32f(vd);
            }
        }
        __syncthreads();

        const float4* h0p = reinterpret_cast<const float4*>(hS +    0 + kq * 28);
        const float4* h1p = reinterpret_cast<const float4*>(hS +  896 + kq * 28);
        const float4* h2p = reinterpret_cast<const float4*>(hS + 1792 + kq * 28);
        const float4* h3p = reinterpret_cast<const float4*>(hS + 2688 + kq * 28);
        float a0 = 0, a1 = 0, a2 = 0, a3 = 0;
        #pragma unroll
        for (int j = 0; j < 7; ++j) {
            float4 a = areg[j];
            float4 v0 = h0p[j]; a0 += a.x*v0.x + a.y*v0.y + a.z*v0.z + a.w*v0.w;
            float4 v1 = h1p[j]; a1 += a.x*v1.x + a.y*v1.y + a.z*v1.z + a.w*v1.w;
            float4 v2 = h2p[j]; a2 += a.x*v2.x + a.y*v2.y + a.z*v2.z + a.w*v2.w;
            float4 v3 = h3p[j]; a3 += a.x*v3.x + a.y*v3.y + a.z*v3.z + a.w*v3.w;
        }
        a0 += __shfl_xor(a0, 16); a1 += __shfl_xor(a1, 16); a2 += __shfl_xor(a2, 16); a3 += __shfl_xor(a3, 16);
        a0 += __shfl_xor(a0,  8); a1 += __shfl_xor(a1,  8); a2 += __shfl_xor(a2,  8); a3 += __shfl_xor(a3,  8);
        a0 += __shfl_xor(a0,  4); a1 += __shfl_xor(a1,  4); a2 += __shfl_xor(a2,  4); a3 += __shfl_xor(a3,  4);
        a0 += __shfl_xor(a0,  2); a1 += __shfl_xor(a1,  2); a2 += __shfl_xor(a2,  2); a3 += __shfl_xor(a3,  2);
        a0 += __shfl_xor(a0,  1); a1 += __shfl_xor(a1,  1); a2 += __shfl_xor(a2,  1); a3 += __shfl_xor(a3,  1);

        if (kq == 0) {
            float z[4] = { a0 + xb0, a1 + xb1, a2 + xb2, a3 + xb3 };
            float hv[4];
            #pragma unroll
            for (int b = 0; b < 4; ++b) {
                float zz = fminf(fmaxf(z[b], -15.f), 15.f);
                float e  = __expf(2.f * zz);
                hv[b] = (e - 1.f) / (e + 1.f);
            }
            unsigned long long lo =
                (unsigned long long)__builtin_bit_cast(unsigned int, hv[0]) |
                ((unsigned long long)__builtin_bit_cast(unsigned int, hv[1]) << 32);
            unsigned long long hi =
                (unsigned long long)__builtin_bit_cast(unsigned int, hv[2]) |
                ((unsigned long long)__builtin_bit_cast(unsigned int, hv[3]) << 32);
            unsigned long long* yp = Y + (long)(t - 1) * 1792 + 2 * row;
            __hip_atomic_store(&yp[0], lo, __ATOMIC_RELAXED, __HIP_MEMORY_SCOPE_AGENT);
            __hip_atomic_store(&yp[1], hi, __ATOMIC_RELAXED, __HIP_MEMORY_SCOPE_AGENT);
            #pragma unroll
            for (int b = 0; b < 4; ++b)
                hs16[(long)b * 917504 + so] = (bf16)hv[b];
        }
        __syncthreads();
    }
}

// ---------------------------------------------------------------------------
// Flash attention body (r9-proven): vectorized staging + vectorized QK inner.
// ---------------------------------------------------------------------------
__device__ __forceinline__ void attn_body(const float* __restrict__ qkv,
                                          bf16* __restrict__ ctx16,
                                          float* ldsf, int bid2)
{
    float* qS = ldsf;
    float* pS = qS + 1792;
    float* rS = pS + 2112;
    float* lS = rS + 32;
    bf16*  kS = (bf16*)(lS + 32);
    bf16*  vS = kS + 3840;

    const int tid = threadIdx.x;
    const int qc = bid2 & 31;
    const int h  = (bid2 >> 5) & 15;
    const int b  = bid2 >> 9;
    const long base = (long)b * 1024 * 2688;
    const int q0 = qc * 32;
    const int hoff = h * 56;

    if (tid < 448) {   // 32 rows x 14 float4-chunks
        int r = tid / 14, c = (tid - r * 14) * 4;
        float4 v = *reinterpret_cast<const float4*>(
            &qkv[base + (long)(q0 + r) * 2688 + hoff + c]);
        const float SC = 0.13363062095621f;
        *reinterpret_cast<float4*>(qS + r * 56 + c) =
            float4{v.x * SC, v.y * SC, v.z * SC, v.w * SC};
    }

    const int w = tid >> 6, l = tid & 63;
    const int qrow = 4 * w;
    const int oq = tid >> 4, ods = tid & 15;
    float m0 = -3e38f, m1 = -3e38f, m2 = -3e38f, m3 = -3e38f;
    float s_l0 = 0, s_l1 = 0, s_l2 = 0, s_l3 = 0;
    float o0 = 0, o1 = 0, o2 = 0, o3 = 0;

    for (int kt = 0; kt < 16; ++kt) {
        __syncthreads();
        for (int idx = tid; idx < 1792; idx += 512) {
            int isv = idx >= 896;
            int e = isv ? idx - 896 : idx;
            int r = e / 14, c = (e - r * 14) * 4;
            float4 v = *reinterpret_cast<const float4*>(
                &qkv[base + (long)(kt * 64 + r) * 2688 + (isv ? 1792 : 896) + hoff + c]);
            bf16x4 o; o[0] = (bf16)v.x; o[1] = (bf16)v.y; o[2] = (bf16)v.z; o[3] = (bf16)v.w;
            *reinterpret_cast<bf16x4*>((isv ? vS : kS) + r * 60 + c) = o;
        }
        __syncthreads();

        float s0 = 0, s1 = 0, s2 = 0, s3 = 0;
        const float* qp = qS + qrow * 56;
        const bf16* kp = kS + l * 60;
        #pragma unroll
        for (int d = 0; d < 56; d += 4) {
            bf16x4 k4 = *reinterpret_cast<const bf16x4*>(kp + d);
            float k0 = (float)k4[0], k1 = (float)k4[1], k2 = (float)k4[2], k3 = (float)k4[3];
            float4 q0v = *reinterpret_cast<const float4*>(qp + d);
            float4 q1v = *reinterpret_cast<const float4*>(qp + 56 + d);
            float4 q2v = *reinterpret_cast<const float4*>(qp + 112 + d);
            float4 q3v = *reinterpret_cast<const float4*>(qp + 168 + d);
            s0 += q0v.x * k0 + q0v.y * k1 + q0v.z * k2 + q0v.w * k3;
            s1 += q1v.x * k0 + q1v.y * k1 + q1v.z * k2 + q1v.w * k3;
            s2 += q2v.x * k0 + q2v.y * k1 + q2v.z * k2 + q2v.w * k3;
            s3 += q3v.x * k0 + q3v.y * k1 + q3v.z * k2 + q3v.w * k3;
        }
        float x0 = s0, x1 = s1, x2 = s2, x3 = s3;
        #pragma unroll
        for (int off = 32; off >= 1; off >>= 1) {
            x0 = fmaxf(x0, __shfl_xor(x0, off));
            x1 = fmaxf(x1, __shfl_xor(x1, off));
            x2 = fmaxf(x2, __shfl_xor(x2, off));
            x3 = fmaxf(x3, __shfl_xor(x3, off));
        }
        float nm0 = fmaxf(m0, x0), nm1 = fmaxf(m1, x1);
        float nm2 = fmaxf(m2, x2), nm3 = fmaxf(m3, x3);
        float p0 = __expf(s0 - nm0), p1 = __expf(s1 - nm1);
        float p2 = __expf(s2 - nm2), p3 = __expf(s3 - nm3);
        float sc0 = __expf(m0 - nm0), sc1 = __expf(m1 - nm1);
        float sc2 = __expf(m2 - nm2), sc3 = __expf(m3 - nm3);
        float t0 = p0, t1 = p1, t2 = p2, t3 = p3;
        #pragma unroll
        for (int off = 32; off >= 1; off >>= 1) {
            t0 += __shfl_xor(t0, off); t1 += __shfl_xor(t1, off);
            t2 += __shfl_xor(t2, off); t3 += __shfl_xor(t3, off);
        }
        s_l0 = s_l0 * sc0 + t0; s_l1 = s_l1 * sc1 + t1;
        s_l2 = s_l2 * sc2 + t2; s_l3 = s_l3 * sc3 + t3;
        m0 = nm0; m1 = nm1; m2 = nm2; m3 = nm3;
        pS[(qrow + 0) * 66 + l] = p0; pS[(qrow + 1) * 66 + l] = p1;
        pS[(qrow + 2) * 66 + l] = p2; pS[(qrow + 3) * 66 + l] = p3;
        if (l == 0) { rS[qrow] = sc0; rS[qrow+1] = sc1; rS[qrow+2] = sc2; rS[qrow+3] = sc3; }
        __syncthreads();

        float rf = rS[oq];
        o0 *= rf; o1 *= rf; o2 *= rf; o3 *= rf;
        const float* pp = pS + oq * 66;
        #pragma unroll 4
        for (int kk = 0; kk < 64; ++kk) {
            float p = pp[kk];
            const bf16* vp = vS + kk * 60 + ods;
            o0 += p * (float)vp[0];
            o1 += p * (float)vp[16];
            o2 += p * (float)vp[32];
            if (ods < 8) o3 += p * (float)vp[48];
        }
    }
    __syncthreads();
    if (l == 0) {
        lS[qrow]     = 1.f / s_l0; lS[qrow + 1] = 1.f / s_l1;
        lS[qrow + 2] = 1.f / s_l2; lS[qrow + 3] = 1.f / s_l3;
    }
    __syncthreads();
    float inv = lS[oq];
    bf16* cp = ctx16 + ((long)b * 1024 + q0 + oq) * 896 + hoff + ods;
    cp[0]  = (bf16)(o0 * inv);
    cp[16] = (bf16)(o1 * inv);
    cp[32] = (bf16)(o2 * inv);
    if (ods < 8) cp[48] = (bf16)(o3 * inv);
}

__global__ __launch_bounds__(512)
void scan_attn_kernel(const float* __restrict__ Amat, const float* __restrict__ xB,
                      bf16* __restrict__ hs16, unsigned long long* __restrict__ Y,
                      const float* __restrict__ qkv, bf16* __restrict__ ctx16)
{
    __shared__ float ldsf[7872];
    if (blockIdx.x < NBLK_SCAN)
        scan_body(Amat, xB, hs16, Y, ldsf);
    else
        attn_body(qkv, ctx16, ldsf, blockIdx.x - NBLK_SCAN);
}

// ---------------------------------------------------------------------------
// Two LayerNorms -> combined fp32 (gate_mix) + combined bf16 (fuse GEMM)
// ---------------------------------------------------------------------------
__global__ __launch_bounds__(256)
void ln2_kernel(const float* __restrict__ s_in, const float* __restrict__ a_in,
                const float* __restrict__ gs, const float* __restrict__ bs,
                const float* __restrict__ ga, const float* __restrict__ ba,
                float* __restrict__ comb, bf16* __restrict__ comb16)
{
    const int wv = threadIdx.x >> 6, ln = threadIdx.x & 63;
    const long row = (long)blockIdx.x * 4 + wv;
    const bool is_a = (blockIdx.y != 0);
    const float* src = (is_a ? a_in : s_in) + row * 896;
    float v[14]; float sum = 0, sq = 0;
    #pragma unroll
    for (int j = 0; j < 14; ++j) { v[j] = src[ln + j * 64]; sum += v[j]; sq += v[j] * v[j]; }
    #pragma unroll
    for (int off = 32; off >= 1; off >>= 1) { sum += __shfl_xor(sum, off); sq += __shfl_xor(sq, off); }
    const float mean = sum * (1.0f / 896.0f);
    const float var  = sq * (1.0f / 896.0f) - mean * mean;
    const float inv  = rsqrtf(var + 1e-5f);
    const float* g  = is_a ? ga : gs;
    const float* bb = is_a ? ba : bs;
    float* dst   = comb   + row * 1792 + (is_a ? 896 : 0);
    bf16*  dst16 = comb16 + row * 1792 + (is_a ? 896 : 0);
    #pragma unroll
    for (int j = 0; j < 14; ++j) {
        int i = ln + j * 64;
        float o = (v[j] - mean) * inv * g[i] + bb[i];
        dst[i] = o;
        dst16[i] = (bf16)o;
    }
}

// ---------------------------------------------------------------------------
// Gates + final mix -> d_out
// ---------------------------------------------------------------------------
__global__ __launch_bounds__(256)
void gate_mix_kernel(const float* __restrict__ fused, const float* __restrict__ gw,
                     const float* __restrict__ gb, const float* __restrict__ comb,
                     float* __restrict__ out)
{
    const int tid = threadIdx.x;
    const int seg = tid & 15;
    const long row = (long)blockIdx.x * 16 + (tid >> 4);
    const float* fr = fused + row * 896;
    float d0 = 0, d1 = 0;
    for (int i = seg; i < 896; i += 16) {
        float f = fr[i];
        d0 += f * gw[i];
        d1 += f * gw[896 + i];
    }
    #pragma unroll
    for (int off = 8; off >= 1; off >>= 1) { d0 += __shfl_xor(d0, off); d1 += __shfl_xor(d1, off); }
    float l0 = d0 + gb[0], l1 = d1 + gb[1];
    float m = fmaxf(l0, l1);
    float e0 = __expf(l0 - m), e1 = __expf(l1 - m);
    float inv = 1.0f / (e0 + e1);
    float g0 = e0 * inv, g1 = e1 * inv;
    const float* cr = comb + row * 1792;
    float* orow = out + row * 896;
    for (int i = seg; i < 896; i += 16)
        orow[i] = g0 * cr[i] + g1 * cr[896 + i];
}

// ---------------------------------------------------------------------------
extern "C" void kernel_launch(void* const* d_in, const int* in_sizes, int n_in,
                              void* d_out, int out_size, void* d_ws, size_t ws_size,
                              hipStream_t stream)
{
    (void)in_sizes; (void)n_in; (void)out_size; (void)ws_size;
    const float* x         = (const float*)d_in[0];
    const float* Amat      = (const float*)d_in[1];
    const float* Bm        = (const float*)d_in[2];
    const float* Cm        = (const float*)d_in[3];
    const float* ssm_in_w  = (const float*)d_in[4];
    const float* ssm_in_b  = (const float*)d_in[5];
    const float* ssm_out_w = (const float*)d_in[6];
    const float* ssm_out_b = (const float*)d_in[7];
    const float* qkv_w     = (const float*)d_in[8];
    const float* qkv_b     = (const float*)d_in[9];
    const float* attn_w    = (const float*)d_in[10];
    const float* attn_b    = (const float*)d_in[11];
    const float* proj_w    = (const float*)d_in[12];
    const float* proj_b    = (const float*)d_in[13];
    const float* ln_sg     = (const float*)d_in[14];
    const float* ln_sb     = (const float*)d_in[15];
    const float* ln_ag     = (const float*)d_in[16];
    const float* ln_ab     = (const float*)d_in[17];
    const float* fuse_w    = (const float*)d_in[18];
    const float* fuse_b    = (const float*)d_in[19];
    const float* gate_w    = (const float*)d_in[20];
    const float* gate_b    = (const float*)d_in[21];

    float* wsf = (float*)d_ws;
    char*  wsb = (char*)d_ws;

    // ------ workspace layout: max 146.8 MB ------
    // attn_out moved to the dead-qkv region (r11 race fix): it is written by
    // gAO concurrently with gSO reading ys16, so it must NOT overlap ys16.
    unsigned long long* Y = (unsigned long long*)wsb;
    float* xB       = wsf + 3670016;
    float* qkv      = wsf + 7340032;
    float* attn_out = wsf + 7340032;    // over dead qkv [29.36M..44.04M)
    float* ssm_out  = wsf + 22020096;
    float* combf    = wsf + 25690112;
    bf16* comb16 = (bf16*)wsb;
    bf16* ssm_in_w16 = (bf16*)(wsb + 73400320);
    bf16* Bm16       = (bf16*)(wsb + 75005952);
    bf16* qkv_w16    = (bf16*)(wsb + 76611584);
    bf16* hs16   = (bf16*)(wsb + 73400320);
    bf16* ys16   = (bf16*)(wsb + 80740352);
    bf16* Cm16        = (bf16*)(wsb + 14680064);
    bf16* ssm_out_w16 = (bf16*)(wsb + 16285696);
    bf16* attn_w16    = (bf16*)(wsb + 17891328);
    bf16* proj_w16    = (bf16*)(wsb + 19496960);
    bf16* fuse_w16    = (bf16*)(wsb + 21102592);
    bf16* ctx16  = (bf16*)(wsb + 102760448);
    bf16* t116   = (bf16*)(wsb + 110100480);
    bf16* x16    = (bf16*)(wsb + 132120576);
    bf16* xp16   = (bf16*)(wsb + 139460608);

    hipMemsetAsync(Y, 0xFF, 14680064, stream);

    // cvt#1: x + early weights
    CvtArgs c1{};
    c1.src[0] = x;        c1.dst[0] = x16;        c1.rows[0] = 1; c1.cols[0] = 3670016; c1.src_ld[0] = 3670016;
    c1.src[1] = ssm_in_w; c1.dst[1] = ssm_in_w16; c1.rows[1] = 1; c1.cols[1] = 802816;  c1.src_ld[1] = 802816;
    c1.src[2] = Bm;       c1.dst[2] = Bm16;       c1.rows[2] = 1; c1.cols[2] = 802816;  c1.src_ld[2] = 802816;
    c1.src[3] = qkv_w;    c1.dst[3] = qkv_w16;    c1.rows[3] = 1; c1.cols[3] = 2408448; c1.src_ld[3] = 2408448;
    c1.src[4] = x;        c1.dst[4] = x16;        c1.rows[4] = 1; c1.cols[4] = 0;       c1.src_ld[4] = 4;
    cvt_kernel<<<dim3(64, 4), 256, 0, stream>>>(c1);

    // front: batched {xp16 GEMM, qkv GEMM} (both read x16; disjoint writes)
    GemmProb gXP { x16, ssm_in_w16, ssm_in_b, nullptr, xp16, 896, 896, 7 };
    GemmProb gQKV{ x16, qkv_w16,    qkv_b,    qkv, nullptr, 2688, 896, 21 };
    gemm2_kernel<<<dim3(21, 32, 2), 256, 0, stream>>>(gXP, gQKV);
    // xB = xp16 @ Bm^T
    GemmProb gXB { xp16, Bm16, nullptr, xB, nullptr, 896, 896, 7 };
    gemm_bf16_kernel<<<dim3(7, 32), 256, 0, stream>>>(gXB);
    // fused: scan (blocks 0..55, prio 3) + flash attention (blocks 56..2103)
    scan_attn_kernel<<<NBLK_SCAN + 2048, 512, 0, stream>>>(Amat, xB, hs16, Y, qkv, ctx16);

    // cvt#2: late weights into dead xB region
    CvtArgs c2{};
    c2.src[0] = Cm;        c2.dst[0] = Cm16;        c2.rows[0] = 1;   c2.cols[0] = 802816; c2.src_ld[0] = 802816;
    c2.src[1] = ssm_out_w; c2.dst[1] = ssm_out_w16; c2.rows[1] = 1;   c2.cols[1] = 802816; c2.src_ld[1] = 802816;
    c2.src[2] = attn_w;    c2.dst[2] = attn_w16;    c2.rows[2] = 1;   c2.cols[2] = 802816; c2.src_ld[2] = 802816;
    c2.src[3] = proj_w;    c2.dst[3] = proj_w16;    c2.rows[3] = 1;   c2.cols[3] = 802816; c2.src_ld[3] = 802816;
    c2.src[4] = fuse_w;    c2.dst[4] = fuse_w16;    c2.rows[4] = 896; c2.cols[4] = 1792;   c2.src_ld[4] = 2688;
    cvt_kernel<<<dim3(64, 5), 256, 0, stream>>>(c2);

    // tails, pairwise batched (read/write sets disjoint within each launch):
    // {ys16 = hs16@Cm^T, t116 = ctx16@attn_w^T+b}
    GemmProb gYS { hs16,  Cm16,     nullptr, nullptr, ys16, 896, 896, 7 };
    GemmProb gT1 { ctx16, attn_w16, attn_b,  nullptr, t116, 896, 896, 7 };
    gemm2_kernel<<<dim3(7, 32, 2), 256, 0, stream>>>(gYS, gT1);
    // {ssm_out = ys16@ssm_out_w^T+b, attn_out = t116@proj_w^T+b}
    GemmProb gSO { ys16, ssm_out_w16, ssm_out_b, ssm_out, nullptr, 896, 896, 7 };
    GemmProb gAO { t116, proj_w16,    proj_b,    attn_out, nullptr, 896, 896, 7 };
    gemm2_kernel<<<dim3(7, 32, 2), 256, 0, stream>>>(gSO, gAO);
    // norms -> combined (fp32 + bf16)
    ln2_kernel<<<dim3(1024, 2), 256, 0, stream>>>(ssm_out, attn_out, ln_sg, ln_sb, ln_ag, ln_ab, combf, comb16);
    // fused = comb16 @ fuse_w16^T + b
    GemmProb gFU { comb16, fuse_w16, fuse_b, ssm_out, nullptr, 896, 1792, 7 };
    gemm_bf16_kernel<<<dim3(7, 32), 256, 0, stream>>>(gFU);
    // gates + mix -> out
    gate_mix_kernel<<<256, 256, 0, stream>>>(ssm_out, gate_w, gate_b, combf, (float*)d_out);
}

// Round 14
// 2902.045 us; speedup vs baseline: 1.2082x; 1.0126x over previous
//
#include <hip/hip_runtime.h>
#include <hip/hip_bf16.h>

typedef __bf16 bf16;
typedef __bf16 bf16x8 __attribute__((ext_vector_type(8)));
typedef __bf16 bf16x4 __attribute__((ext_vector_type(4)));
typedef float  f32x4  __attribute__((ext_vector_type(4)));

#define AS1 __attribute__((address_space(1)))
#define AS3 __attribute__((address_space(3)))

// ---------------------------------------------------------------------------
// f32 -> bf16 convert, up to 5 tensors per launch, strided rows.
// ---------------------------------------------------------------------------
struct CvtArgs {
    const float* src[5];
    bf16* dst[5];
    int rows[5], cols[5], src_ld[5];
};

__global__ __launch_bounds__(256)
void cvt_kernel(CvtArgs a)
{
    const int t = blockIdx.y;
    const float* s = a.src[t];
    bf16* d = a.dst[t];
    const int cols = a.cols[t];
    const long total = (long)a.rows[t] * cols;
    const int ld = a.src_ld[t];
    for (long i = ((long)blockIdx.x * 256 + threadIdx.x) * 4; i < total;
         i += (long)gridDim.x * 1024) {
        long r = i / cols, c = i - r * cols;      // cols % 4 == 0: chunks don't cross rows
        float4 v = *reinterpret_cast<const float4*>(s + r * ld + c);
        bf16x4 o; o[0] = (bf16)v.x; o[1] = (bf16)v.y; o[2] = (bf16)v.z; o[3] = (bf16)v.w;
        *reinterpret_cast<bf16x4*>(d + i) = o;
    }
}

// ---------------------------------------------------------------------------
// GEMM (m97 structure): C[M,N] = A[M,K] * B[N,K]^T (+bias). bf16 in, fp32 acc.
// 128x128 tile, BK=64, 4 waves, global_load_lds width-16, linear LDS. M=4096.
// gemm2_kernel: TWO independent problems batched on blockIdx.z.
// RACE RULE (r11/r13 lessons): problems batched in one launch must have fully
// disjoint {read set} x {write set}; dead-region reuse is only legal across
// launch boundaries; combf is 29.36 MB (1792 cols fp32), not 14.68.
// ---------------------------------------------------------------------------
struct GemmProb {
    const bf16* A;
    const bf16* B;
    const float* bias;
    float* Cf;
    bf16* Cb;
    int N, K, gx;
};

__device__ __forceinline__ void gemm_body(const GemmProb& p,
                                          bf16* As, bf16* Bs)
{
    const int N = p.N, K = p.K;
    const int tid = threadIdx.x;
    const long bm = (long)blockIdx.y * 128;
    const long bn = (long)blockIdx.x * 128;
    const int w  = tid >> 6, l = tid & 63;
    const int wm = (w >> 1) * 64, wn = (w & 1) * 64;
    const int lr = l & 15, lk = (l >> 4) * 8;

    const int srow = tid >> 3;          // 0..31
    const int scol = (tid & 7) * 8;     // 0,8,..,56
    const bf16* Ag = p.A + (bm + srow) * (long)K + scol;
    const bf16* Bg = p.B + (bn + srow) * (long)K + scol;
    bf16* AsW = As + srow * 64 + scol;
    bf16* BsW = Bs + srow * 64 + scol;

    f32x4 acc[4][4];
    #pragma unroll
    for (int i = 0; i < 4; ++i)
        #pragma unroll
        for (int j = 0; j < 4; ++j)
            acc[i][j] = f32x4{0.f, 0.f, 0.f, 0.f};

    for (int kt = 0; kt < K; kt += 64) {
        #pragma unroll
        for (int i = 0; i < 4; ++i) {
            __builtin_amdgcn_global_load_lds(
                (const AS1 void*)(Ag + (long)i * 32 * K + kt),
                (AS3 void*)(AsW + i * 2048), 16, 0, 0);
            __builtin_amdgcn_global_load_lds(
                (const AS1 void*)(Bg + (long)i * 32 * K + kt),
                (AS3 void*)(BsW + i * 2048), 16, 0, 0);
        }
        __syncthreads();
        #pragma unroll
        for (int kk = 0; kk < 64; kk += 32) {
            bf16x8 a[4], b[4];
            #pragma unroll
            for (int i = 0; i < 4; ++i) {
                a[i] = *reinterpret_cast<const bf16x8*>(&As[(wm + i * 16 + lr) * 64 + kk + lk]);
                b[i] = *reinterpret_cast<const bf16x8*>(&Bs[(wn + i * 16 + lr) * 64 + kk + lk]);
            }
            #pragma unroll
            for (int i = 0; i < 4; ++i)
                #pragma unroll
                for (int j = 0; j < 4; ++j)
                    acc[i][j] = __builtin_amdgcn_mfma_f32_16x16x32_bf16(a[i], b[j], acc[i][j], 0, 0, 0);
        }
        __syncthreads();
    }
    const int crow = wm + (l >> 4) * 4;
    const int ccol = wn + (l & 15);
    #pragma unroll
    for (int i = 0; i < 4; ++i)
        #pragma unroll
        for (int j = 0; j < 4; ++j) {
            long col = bn + ccol + j * 16;
            float bv = p.bias ? p.bias[col] : 0.0f;
            #pragma unroll
            for (int r = 0; r < 4; ++r) {
                long row = bm + crow + i * 16 + r;
                float v = acc[i][j][r] + bv;
                if (p.Cf) p.Cf[row * (long)N + col] = v;
                if (p.Cb) p.Cb[row * (long)N + col] = (bf16)v;
            }
        }
}

__global__ __launch_bounds__(256, 2)
void gemm_bf16_kernel(GemmProb p)
{
    __shared__ bf16 As[128 * 64];
    __shared__ bf16 Bs[128 * 64];
    gemm_body(p, As, Bs);
}

__global__ __launch_bounds__(256, 2)
void gemm2_kernel(GemmProb p0, GemmProb p1)
{
    __shared__ bf16 As[128 * 64];
    __shared__ bf16 Bs[128 * 64];
    const GemmProb& p = blockIdx.z ? p1 : p0;
    if ((int)blockIdx.x >= p.gx) return;
    gemm_body(p, As, Bs);
}

// ---------------------------------------------------------------------------
// Scan sync (r12-proven structure): data-is-the-flag on Y (u64 pairs),
// relaxed agent-scope atomics, parallel poll, full __syncthreads barriers,
// in-loop bf16 hs16 stores. r14 SINGLE-VARIABLE A/B vs r12: NO s_sleep in
// the poll loop (r13's attempt was confounded by a layout NaN bug).
// Pre-committed read: fused <=2.65ms => keep; >=2.75ms => restore sleep.
// ---------------------------------------------------------------------------
#define SENT64 0xFFFFFFFFFFFFFFFFull
#define NBLK_SCAN 56

__device__ __forceinline__ float lo32f(unsigned long long v) {
    return __builtin_bit_cast(float, (unsigned int)v);
}
__device__ __forceinline__ float hi32f(unsigned long long v) {
    return __builtin_bit_cast(float, (unsigned int)(v >> 32));
}

__device__ __forceinline__ void scan_body(const float* __restrict__ Amat,
                                          const float* __restrict__ xB,
                                          bf16* __restrict__ hs16,
                                          unsigned long long* __restrict__ Y,
                                          float* hS)
{
    __builtin_amdgcn_s_setprio(3);
    const int tid = threadIdx.x;
    const int bi  = blockIdx.x;
    const int kq  = tid & 31;      // 32 k-slices of 28
    const int rg  = tid >> 5;      // 16 rows per block
    const int row = bi * 16 + rg;

    float4 areg[7];
    {
        const float4* Ap = reinterpret_cast<const float4*>(Amat + (long)row * 896 + kq * 28);
        #pragma unroll
        for (int j = 0; j < 7; ++j) areg[j] = Ap[j];
    }

    const int d0 = tid;
    const int d1 = tid + 512;
    const bool two = (tid < 384);  // wave-uniform

    for (int t = 1; t <= 1024; ++t) {
        const long so = (long)(t - 1) * 896 + row;
        float xb0 = 0, xb1 = 0, xb2 = 0, xb3 = 0;
        if (kq == 0) {
            xb0 = xB[so];
            xb1 = xB[so +  917504];
            xb2 = xB[so + 1835008];
            xb3 = xB[so + 2752512];
        }

        if (t == 1) {
            #pragma unroll
            for (int j = 0; j < 7; ++j) hS[tid + j * 512] = 0.0f;
        } else {
            const unsigned long long* Yp = Y + (long)(t - 2) * 1792;
            unsigned long long va, vb, vc = 0, vd = 0;
            for (;;) {
                va = __hip_atomic_load(&Yp[2 * d0],     __ATOMIC_RELAXED, __HIP_MEMORY_SCOPE_AGENT);
                vb = __hip_atomic_load(&Yp[2 * d0 + 1], __ATOMIC_RELAXED, __HIP_MEMORY_SCOPE_AGENT);
                bool ok = (va != SENT64) & (vb != SENT64);
                if (two) {
                    vc = __hip_atomic_load(&Yp[2 * d1],     __ATOMIC_RELAXED, __HIP_MEMORY_SCOPE_AGENT);
                    vd = __hip_atomic_load(&Yp[2 * d1 + 1], __ATOMIC_RELAXED, __HIP_MEMORY_SCOPE_AGENT);
                    ok &= (vc != SENT64) & (vd != SENT64);
                }
                if (ok) break;
            }
            hS[       d0] = lo32f(va);
            hS[ 896 + d0] = hi32f(va);
            hS[1792 + d0] = lo32f(vb);
            hS[2688 + d0] = hi32f(vb);
            if (two) {
                hS[       d1] = lo32f(vc);
                hS[ 896 + d1] = hi32f(vc);
                hS[1792 + d1] = lo32f(vd);
                hS[2688 + d1] = hi32f(vd);
            }
        }
        __syncthreads();

        const float4* h0p = reinterpret_cast<const float4*>(hS +    0 + kq * 28);
        const float4* h1p = reinterpret_cast<const float4*>(hS +  896 + kq * 28);
        const float4* h2p = reinterpret_cast<const float4*>(hS + 1792 + kq * 28);
        const float4* h3p = reinterpret_cast<const float4*>(hS + 2688 + kq * 28);
        float a0 = 0, a1 = 0, a2 = 0, a3 = 0;
        #pragma unroll
        for (int j = 0; j < 7; ++j) {
            float4 a = areg[j];
            float4 v0 = h0p[j]; a0 += a.x*v0.x + a.y*v0.y + a.z*v0.z + a.w*v0.w;
            float4 v1 = h1p[j]; a1 += a.x*v1.x + a.y*v1.y + a.z*v1.z + a.w*v1.w;
            float4 v2 = h2p[j]; a2 += a.x*v2.x + a.y*v2.y + a.z*v2.z + a.w*v2.w;
            float4 v3 = h3p[j]; a3 += a.x*v3.x + a.y*v3.y + a.z*v3.z + a.w*v3.w;
        }
        a0 += __shfl_xor(a0, 16); a1 += __shfl_xor(a1, 16); a2 += __shfl_xor(a2, 16); a3 += __shfl_xor(a3, 16);
        a0 += __shfl_xor(a0,  8); a1 += __shfl_xor(a1,  8); a2 += __shfl_xor(a2,  8); a3 += __shfl_xor(a3,  8);
        a0 += __shfl_xor(a0,  4); a1 += __shfl_xor(a1,  4); a2 += __shfl_xor(a2,  4); a3 += __shfl_xor(a3,  4);
        a0 += __shfl_xor(a0,  2); a1 += __shfl_xor(a1,  2); a2 += __shfl_xor(a2,  2); a3 += __shfl_xor(a3,  2);
        a0 += __shfl_xor(a0,  1); a1 += __shfl_xor(a1,  1); a2 += __shfl_xor(a2,  1); a3 += __shfl_xor(a3,  1);

        if (kq == 0) {
            float z[4] = { a0 + xb0, a1 + xb1, a2 + xb2, a3 + xb3 };
            float hv[4];
            #pragma unroll
            for (int b = 0; b < 4; ++b) {
                float zz = fminf(fmaxf(z[b], -15.f), 15.f);
                float e  = __expf(2.f * zz);
                hv[b] = (e - 1.f) / (e + 1.f);
            }
            unsigned long long lo =
                (unsigned long long)__builtin_bit_cast(unsigned int, hv[0]) |
                ((unsigned long long)__builtin_bit_cast(unsigned int, hv[1]) << 32);
            unsigned long long hi =
                (unsigned long long)__builtin_bit_cast(unsigned int, hv[2]) |
                ((unsigned long long)__builtin_bit_cast(unsigned int, hv[3]) << 32);
            unsigned long long* yp = Y + (long)(t - 1) * 1792 + 2 * row;
            __hip_atomic_store(&yp[0], lo, __ATOMIC_RELAXED, __HIP_MEMORY_SCOPE_AGENT);
            __hip_atomic_store(&yp[1], hi, __ATOMIC_RELAXED, __HIP_MEMORY_SCOPE_AGENT);
            #pragma unroll
            for (int b = 0; b < 4; ++b)
                hs16[(long)b * 917504 + so] = (bf16)hv[b];
        }
        __syncthreads();
    }
}

// ---------------------------------------------------------------------------
// Flash attention body (r9-proven): vectorized staging + vectorized QK inner.
// ---------------------------------------------------------------------------
__device__ __forceinline__ void attn_body(const float* __restrict__ qkv,
                                          bf16* __restrict__ ctx16,
                                          float* ldsf, int bid2)
{
    float* qS = ldsf;
    float* pS = qS + 1792;
    float* rS = pS + 2112;
    float* lS = rS + 32;
    bf16*  kS = (bf16*)(lS + 32);
    bf16*  vS = kS + 3840;

    const int tid = threadIdx.x;
    const int qc = bid2 & 31;
    const int h  = (bid2 >> 5) & 15;
    const int b  = bid2 >> 9;
    const long base = (long)b * 1024 * 2688;
    const int q0 = qc * 32;
    const int hoff = h * 56;

    if (tid < 448) {   // 32 rows x 14 float4-chunks
        int r = tid / 14, c = (tid - r * 14) * 4;
        float4 v = *reinterpret_cast<const float4*>(
            &qkv[base + (long)(q0 + r) * 2688 + hoff + c]);
        const float SC = 0.13363062095621f;
        *reinterpret_cast<float4*>(qS + r * 56 + c) =
            float4{v.x * SC, v.y * SC, v.z * SC, v.w * SC};
    }

    const int w = tid >> 6, l = tid & 63;
    const int qrow = 4 * w;
    const int oq = tid >> 4, ods = tid & 15;
    float m0 = -3e38f, m1 = -3e38f, m2 = -3e38f, m3 = -3e38f;
    float s_l0 = 0, s_l1 = 0, s_l2 = 0, s_l3 = 0;
    float o0 = 0, o1 = 0, o2 = 0, o3 = 0;

    for (int kt = 0; kt < 16; ++kt) {
        __syncthreads();
        for (int idx = tid; idx < 1792; idx += 512) {
            int isv = idx >= 896;
            int e = isv ? idx - 896 : idx;
            int r = e / 14, c = (e - r * 14) * 4;
            float4 v = *reinterpret_cast<const float4*>(
                &qkv[base + (long)(kt * 64 + r) * 2688 + (isv ? 1792 : 896) + hoff + c]);
            bf16x4 o; o[0] = (bf16)v.x; o[1] = (bf16)v.y; o[2] = (bf16)v.z; o[3] = (bf16)v.w;
            *reinterpret_cast<bf16x4*>((isv ? vS : kS) + r * 60 + c) = o;
        }
        __syncthreads();

        float s0 = 0, s1 = 0, s2 = 0, s3 = 0;
        const float* qp = qS + qrow * 56;
        const bf16* kp = kS + l * 60;
        #pragma unroll
        for (int d = 0; d < 56; d += 4) {
            bf16x4 k4 = *reinterpret_cast<const bf16x4*>(kp + d);
            float k0 = (float)k4[0], k1 = (float)k4[1], k2 = (float)k4[2], k3 = (float)k4[3];
            float4 q0v = *reinterpret_cast<const float4*>(qp + d);
            float4 q1v = *reinterpret_cast<const float4*>(qp + 56 + d);
            float4 q2v = *reinterpret_cast<const float4*>(qp + 112 + d);
            float4 q3v = *reinterpret_cast<const float4*>(qp + 168 + d);
            s0 += q0v.x * k0 + q0v.y * k1 + q0v.z * k2 + q0v.w * k3;
            s1 += q1v.x * k0 + q1v.y * k1 + q1v.z * k2 + q1v.w * k3;
            s2 += q2v.x * k0 + q2v.y * k1 + q2v.z * k2 + q2v.w * k3;
            s3 += q3v.x * k0 + q3v.y * k1 + q3v.z * k2 + q3v.w * k3;
        }
        float x0 = s0, x1 = s1, x2 = s2, x3 = s3;
        #pragma unroll
        for (int off = 32; off >= 1; off >>= 1) {
            x0 = fmaxf(x0, __shfl_xor(x0, off));
            x1 = fmaxf(x1, __shfl_xor(x1, off));
            x2 = fmaxf(x2, __shfl_xor(x2, off));
            x3 = fmaxf(x3, __shfl_xor(x3, off));
        }
        float nm0 = fmaxf(m0, x0), nm1 = fmaxf(m1, x1);
        float nm2 = fmaxf(m2, x2), nm3 = fmaxf(m3, x3);
        float p0 = __expf(s0 - nm0), p1 = __expf(s1 - nm1);
        float p2 = __expf(s2 - nm2), p3 = __expf(s3 - nm3);
        float sc0 = __expf(m0 - nm0), sc1 = __expf(m1 - nm1);
        float sc2 = __expf(m2 - nm2), sc3 = __expf(m3 - nm3);
        float t0 = p0, t1 = p1, t2 = p2, t3 = p3;
        #pragma unroll
        for (int off = 32; off >= 1; off >>= 1) {
            t0 += __shfl_xor(t0, off); t1 += __shfl_xor(t1, off);
            t2 += __shfl_xor(t2, off); t3 += __shfl_xor(t3, off);
        }
        s_l0 = s_l0 * sc0 + t0; s_l1 = s_l1 * sc1 + t1;
        s_l2 = s_l2 * sc2 + t2; s_l3 = s_l3 * sc3 + t3;
        m0 = nm0; m1 = nm1; m2 = nm2; m3 = nm3;
        pS[(qrow + 0) * 66 + l] = p0; pS[(qrow + 1) * 66 + l] = p1;
        pS[(qrow + 2) * 66 + l] = p2; pS[(qrow + 3) * 66 + l] = p3;
        if (l == 0) { rS[qrow] = sc0; rS[qrow+1] = sc1; rS[qrow+2] = sc2; rS[qrow+3] = sc3; }
        __syncthreads();

        float rf = rS[oq];
        o0 *= rf; o1 *= rf; o2 *= rf; o3 *= rf;
        const float* pp = pS + oq * 66;
        #pragma unroll 4
        for (int kk = 0; kk < 64; ++kk) {
            float p = pp[kk];
            const bf16* vp = vS + kk * 60 + ods;
            o0 += p * (float)vp[0];
            o1 += p * (float)vp[16];
            o2 += p * (float)vp[32];
            if (ods < 8) o3 += p * (float)vp[48];
        }
    }
    __syncthreads();
    if (l == 0) {
        lS[qrow]     = 1.f / s_l0; lS[qrow + 1] = 1.f / s_l1;
        lS[qrow + 2] = 1.f / s_l2; lS[qrow + 3] = 1.f / s_l3;
    }
    __syncthreads();
    float inv = lS[oq];
    bf16* cp = ctx16 + ((long)b * 1024 + q0 + oq) * 896 + hoff + ods;
    cp[0]  = (bf16)(o0 * inv);
    cp[16] = (bf16)(o1 * inv);
    cp[32] = (bf16)(o2 * inv);
    if (ods < 8) cp[48] = (bf16)(o3 * inv);
}

__global__ __launch_bounds__(512)
void scan_attn_kernel(const float* __restrict__ Amat, const float* __restrict__ xB,
                      bf16* __restrict__ hs16, unsigned long long* __restrict__ Y,
                      const float* __restrict__ qkv, bf16* __restrict__ ctx16)
{
    __shared__ float ldsf[7872];
    if (blockIdx.x < NBLK_SCAN)
        scan_body(Amat, xB, hs16, Y, ldsf);
    else
        attn_body(qkv, ctx16, ldsf, blockIdx.x - NBLK_SCAN);
}

// ---------------------------------------------------------------------------
// Two LayerNorms -> combined fp32 (gate_mix) + combined bf16 (fuse GEMM)
// ---------------------------------------------------------------------------
__global__ __launch_bounds__(256)
void ln2_kernel(const float* __restrict__ s_in, const float* __restrict__ a_in,
                const float* __restrict__ gs, const float* __restrict__ bs,
                const float* __restrict__ ga, const float* __restrict__ ba,
                float* __restrict__ comb, bf16* __restrict__ comb16)
{
    const int wv = threadIdx.x >> 6, ln = threadIdx.x & 63;
    const long row = (long)blockIdx.x * 4 + wv;
    const bool is_a = (blockIdx.y != 0);
    const float* src = (is_a ? a_in : s_in) + row * 896;
    float v[14]; float sum = 0, sq = 0;
    #pragma unroll
    for (int j = 0; j < 14; ++j) { v[j] = src[ln + j * 64]; sum += v[j]; sq += v[j] * v[j]; }
    #pragma unroll
    for (int off = 32; off >= 1; off >>= 1) { sum += __shfl_xor(sum, off); sq += __shfl_xor(sq, off); }
    const float mean = sum * (1.0f / 896.0f);
    const float var  = sq * (1.0f / 896.0f) - mean * mean;
    const float inv  = rsqrtf(var + 1e-5f);
    const float* g  = is_a ? ga : gs;
    const float* bb = is_a ? ba : bs;
    float* dst   = comb   + row * 1792 + (is_a ? 896 : 0);
    bf16*  dst16 = comb16 + row * 1792 + (is_a ? 896 : 0);
    #pragma unroll
    for (int j = 0; j < 14; ++j) {
        int i = ln + j * 64;
        float o = (v[j] - mean) * inv * g[i] + bb[i];
        dst[i] = o;
        dst16[i] = (bf16)o;
    }
}

// ---------------------------------------------------------------------------
// Gates + final mix -> d_out
// ---------------------------------------------------------------------------
__global__ __launch_bounds__(256)
void gate_mix_kernel(const float* __restrict__ fused, const float* __restrict__ gw,
                     const float* __restrict__ gb, const float* __restrict__ comb,
                     float* __restrict__ out)
{
    const int tid = threadIdx.x;
    const int seg = tid & 15;
    const long row = (long)blockIdx.x * 16 + (tid >> 4);
    const float* fr = fused + row * 896;
    float d0 = 0, d1 = 0;
    for (int i = seg; i < 896; i += 16) {
        float f = fr[i];
        d0 += f * gw[i];
        d1 += f * gw[896 + i];
    }
    #pragma unroll
    for (int off = 8; off >= 1; off >>= 1) { d0 += __shfl_xor(d0, off); d1 += __shfl_xor(d1, off); }
    float l0 = d0 + gb[0], l1 = d1 + gb[1];
    float m = fmaxf(l0, l1);
    float e0 = __expf(l0 - m), e1 = __expf(l1 - m);
    float inv = 1.0f / (e0 + e1);
    float g0 = e0 * inv, g1 = e1 * inv;
    const float* cr = comb + row * 1792;
    float* orow = out + row * 896;
    for (int i = seg; i < 896; i += 16)
        orow[i] = g0 * cr[i] + g1 * cr[896 + i];
}

// ---------------------------------------------------------------------------
extern "C" void kernel_launch(void* const* d_in, const int* in_sizes, int n_in,
                              void* d_out, int out_size, void* d_ws, size_t ws_size,
                              hipStream_t stream)
{
    (void)in_sizes; (void)n_in; (void)out_size; (void)ws_size;
    const float* x         = (const float*)d_in[0];
    const float* Amat      = (const float*)d_in[1];
    const float* Bm        = (const float*)d_in[2];
    const float* Cm        = (const float*)d_in[3];
    const float* ssm_in_w  = (const float*)d_in[4];
    const float* ssm_in_b  = (const float*)d_in[5];
    const float* ssm_out_w = (const float*)d_in[6];
    const float* ssm_out_b = (const float*)d_in[7];
    const float* qkv_w     = (const float*)d_in[8];
    const float* qkv_b     = (const float*)d_in[9];
    const float* attn_w    = (const float*)d_in[10];
    const float* attn_b    = (const float*)d_in[11];
    const float* proj_w    = (const float*)d_in[12];
    const float* proj_b    = (const float*)d_in[13];
    const float* ln_sg     = (const float*)d_in[14];
    const float* ln_sb     = (const float*)d_in[15];
    const float* ln_ag     = (const float*)d_in[16];
    const float* ln_ab     = (const float*)d_in[17];
    const float* fuse_w    = (const float*)d_in[18];
    const float* fuse_b    = (const float*)d_in[19];
    const float* gate_w    = (const float*)d_in[20];
    const float* gate_b    = (const float*)d_in[21];

    float* wsf = (float*)d_ws;
    char*  wsb = (char*)d_ws;

    // ------ workspace layout (r12-proven, max 146.8 MB) ------
    // combf spans [102.76M, 132.12M) -- 1792 cols fp32 = 29.36 MB (r13 bug).
    // Late weights live in dead-xB [14.68M, 24.31M), converted AFTER the
    // fused kernel (cvt2). attn_out over dead qkv [29.36M, 44.04M).
    unsigned long long* Y = (unsigned long long*)wsb;
    float* xB       = wsf + 3670016;
    float* qkv      = wsf + 7340032;
    float* attn_out = wsf + 7340032;    // over dead qkv [29.36M..44.04M)
    float* ssm_out  = wsf + 22020096;
    float* combf    = wsf + 25690112;
    bf16* comb16 = (bf16*)wsb;
    bf16* ssm_in_w16 = (bf16*)(wsb + 73400320);
    bf16* Bm16       = (bf16*)(wsb + 75005952);
    bf16* qkv_w16    = (bf16*)(wsb + 76611584);
    bf16* hs16   = (bf16*)(wsb + 73400320);
    bf16* ys16   = (bf16*)(wsb + 80740352);
    bf16* Cm16        = (bf16*)(wsb + 14680064);
    bf16* ssm_out_w16 = (bf16*)(wsb + 16285696);
    bf16* attn_w16    = (bf16*)(wsb + 17891328);
    bf16* proj_w16    = (bf16*)(wsb + 19496960);
    bf16* fuse_w16    = (bf16*)(wsb + 21102592);
    bf16* ctx16  = (bf16*)(wsb + 102760448);
    bf16* t116   = (bf16*)(wsb + 110100480);
    bf16* x16    = (bf16*)(wsb + 132120576);
    bf16* xp16   = (bf16*)(wsb + 139460608);

    hipMemsetAsync(Y, 0xFF, 14680064, stream);

    // cvt#1: x + early weights
    CvtArgs c1{};
    c1.src[0] = x;        c1.dst[0] = x16;        c1.rows[0] = 1; c1.cols[0] = 3670016; c1.src_ld[0] = 3670016;
    c1.src[1] = ssm_in_w; c1.dst[1] = ssm_in_w16; c1.rows[1] = 1; c1.cols[1] = 802816;  c1.src_ld[1] = 802816;
    c1.src[2] = Bm;       c1.dst[2] = Bm16;       c1.rows[2] = 1; c1.cols[2] = 802816;  c1.src_ld[2] = 802816;
    c1.src[3] = qkv_w;    c1.dst[3] = qkv_w16;    c1.rows[3] = 1; c1.cols[3] = 2408448; c1.src_ld[3] = 2408448;
    c1.src[4] = x;        c1.dst[4] = x16;        c1.rows[4] = 1; c1.cols[4] = 0;       c1.src_ld[4] = 4;
    cvt_kernel<<<dim3(64, 4), 256, 0, stream>>>(c1);

    // front: batched {xp16 GEMM, qkv GEMM} (both read x16; disjoint writes)
    GemmProb gXP { x16, ssm_in_w16, ssm_in_b, nullptr, xp16, 896, 896, 7 };
    GemmProb gQKV{ x16, qkv_w16,    qkv_b,    qkv, nullptr, 2688, 896, 21 };
    gemm2_kernel<<<dim3(21, 32, 2), 256, 0, stream>>>(gXP, gQKV);
    // xB = xp16 @ Bm^T
    GemmProb gXB { xp16, Bm16, nullptr, xB, nullptr, 896, 896, 7 };
    gemm_bf16_kernel<<<dim3(7, 32), 256, 0, stream>>>(gXB);
    // fused: scan (blocks 0..55, prio 3) + flash attention (blocks 56..2103)
    scan_attn_kernel<<<NBLK_SCAN + 2048, 512, 0, stream>>>(Amat, xB, hs16, Y, qkv, ctx16);

    // cvt#2: late weights into dead xB region
    CvtArgs c2{};
    c2.src[0] = Cm;        c2.dst[0] = Cm16;        c2.rows[0] = 1;   c2.cols[0] = 802816; c2.src_ld[0] = 802816;
    c2.src[1] = ssm_out_w; c2.dst[1] = ssm_out_w16; c2.rows[1] = 1;   c2.cols[1] = 802816; c2.src_ld[1] = 802816;
    c2.src[2] = attn_w;    c2.dst[2] = attn_w16;    c2.rows[2] = 1;   c2.cols[2] = 802816; c2.src_ld[2] = 802816;
    c2.src[3] = proj_w;    c2.dst[3] = proj_w16;    c2.rows[3] = 1;   c2.cols[3] = 802816; c2.src_ld[3] = 802816;
    c2.src[4] = fuse_w;    c2.dst[4] = fuse_w16;    c2.rows[4] = 896; c2.cols[4] = 1792;   c2.src_ld[4] = 2688;
    cvt_kernel<<<dim3(64, 5), 256, 0, stream>>>(c2);

    // tails, pairwise batched (read/write sets disjoint within each launch):
    // {ys16 = hs16@Cm^T, t116 = ctx16@attn_w^T+b}
    GemmProb gYS { hs16,  Cm16,     nullptr, nullptr, ys16, 896, 896, 7 };
    GemmProb gT1 { ctx16, attn_w16, attn_b,  nullptr, t116, 896, 896, 7 };
    gemm2_kernel<<<dim3(7, 32, 2), 256, 0, stream>>>(gYS, gT1);
    // {ssm_out = ys16@ssm_out_w^T+b, attn_out = t116@proj_w^T+b}
    GemmProb gSO { ys16, ssm_out_w16, ssm_out_b, ssm_out, nullptr, 896, 896, 7 };
    GemmProb gAO { t116, proj_w16,    proj_b,    attn_out, nullptr, 896, 896, 7 };
    gemm2_kernel<<<dim3(7, 32, 2), 256, 0, stream>>>(gSO, gAO);
    // norms -> combined (fp32 + bf16)
    ln2_kernel<<<dim3(1024, 2), 256, 0, stream>>>(ssm_out, attn_out, ln_sg, ln_sb, ln_ag, ln_ab, combf, comb16);
    // fused = comb16 @ fuse_w16^T + b
    GemmProb gFU { comb16, fuse_w16, fuse_b, ssm_out, nullptr, 896, 1792, 7 };
    gemm_bf16_kernel<<<dim3(7, 32), 256, 0, stream>>>(gFU);
    // gates + mix -> out
    gate_mix_kernel<<<256, 256, 0, stream>>>(ssm_out, gate_w, gate_b, combf, (float*)d_out);
}